// Round 6
// baseline (260.276 us; speedup 1.0000x reference)
//
#include <hip/hip_runtime.h>

// y[i] = (x[i]*W0 >= x[i]*W1) ? -1.0f : +1.0f
// (argmax over [x*W0, x*W1] with first-max tie-break, then 2*idx-1).
// Both products computed and compared to stay bit-exact with the reference.
//
// Persistent-grid streaming kernel: 1536 blocks x 256 thr (24 waves/CU),
// grid-stride loop unrolled x4 with all 4 independent dwordx4 loads issued
// before any use -> continuous outstanding HBM traffic, no block-retire
// drain (R1..R5 one-shot-thread variants plateaued at ~77us vs 48us copy
// roofline; fills/copies at 6.3-6.6 TB/s all use this persistent shape).

typedef float vf4 __attribute__((ext_vector_type(4)));

__device__ __forceinline__ vf4 signsel(vf4 v, float w0, float w1) {
    vf4 r;
    r.x = (v.x * w0 >= v.x * w1) ? -1.0f : 1.0f;
    r.y = (v.y * w0 >= v.y * w1) ? -1.0f : 1.0f;
    r.z = (v.z * w0 >= v.z * w1) ? -1.0f : 1.0f;
    r.w = (v.w * w0 >= v.w * w1) ? -1.0f : 1.0f;
    return r;
}

__global__ __launch_bounds__(256) void metaconv_stream(
    const vf4* __restrict__ x4,
    const float* __restrict__ W,
    vf4* __restrict__ out4,
    int n4)
{
    const int T = gridDim.x * blockDim.x;     // total threads (grid stride)
    int i = blockIdx.x * blockDim.x + threadIdx.x;
    const float w0 = W[0];   // wave-uniform -> s_load
    const float w1 = W[1];

    // Main loop: 4 independent coalesced loads in flight per thread.
    for (; i + 3 * T < n4; i += 4 * T) {
        vf4 a = x4[i];
        vf4 b = x4[i + T];
        vf4 c = x4[i + 2 * T];
        vf4 d = x4[i + 3 * T];
        out4[i]         = signsel(a, w0, w1);
        out4[i + T]     = signsel(b, w0, w1);
        out4[i + 2 * T] = signsel(c, w0, w1);
        out4[i + 3 * T] = signsel(d, w0, w1);
    }
    // Remainder iterations (none for this problem's N: 9437184 = 24*393216).
    for (; i < n4; i += T) {
        out4[i] = signsel(x4[i], w0, w1);
    }
}

// Scalar tail for n not divisible by 4 (not hit for this problem's N).
__global__ void metaconv_sign_tail(
    const float* __restrict__ x,
    const float* __restrict__ W,
    float* __restrict__ out,
    int start, int n)
{
    int i = start + blockIdx.x * blockDim.x + threadIdx.x;
    float w0 = W[0];
    float w1 = W[1];
    if (i < n) {
        float v = x[i];
        out[i] = (v * w0 >= v * w1) ? -1.0f : 1.0f;
    }
}

extern "C" void kernel_launch(void* const* d_in, const int* in_sizes, int n_in,
                              void* d_out, int out_size, void* d_ws, size_t ws_size,
                              hipStream_t stream)
{
    const float* x = (const float*)d_in[0];
    const float* W = (const float*)d_in[1];
    float* out = (float*)d_out;

    int n = in_sizes[0];          // 2048*2048*3*3 = 37,748,736
    int n4 = n >> 2;              // float4 count = 9,437,184
    int rem = n & 3;

    if (n4 > 0) {
        const int block = 256;
        // 1536 blocks = 6 blocks/CU x 4 waves = 24 waves/CU; n4/(1536*256)=24 iters.
        int grid = 1536;
        int max_grid = (n4 + block - 1) / block;   // don't over-launch tiny n
        if (grid > max_grid) grid = max_grid;
        metaconv_stream<<<grid, block, 0, stream>>>(
            (const vf4*)x, W, (vf4*)out, n4);
    }
    if (rem > 0) {
        metaconv_sign_tail<<<1, 64, 0, stream>>>(x, W, out, n4 << 2, n);
    }
}